// Round 9
// baseline (204.777 us; speedup 1.0000x reference)
//
#include <hip/hip_runtime.h>
#include <hip/hip_fp16.h>

// Fused Conv3d(3->16, 3x3x3, VALID) + bias + channel softmax + maxpool(4,4,4)/4.
// x: [512,3,16,32,32] f32, w: [16,3,3,3,3] f32, b: [16] f32 -> out [512,16,3,7,7] f32
//
// R19: R18 (74.0 us) showed no saturated pipe (VALU 73%, MFMA 19%, HBM 16%)
// with OccupancyPercent 49% vs a 62% resource cap -> latency/occupancy bound.
// This round raises the occupancy CEILING to 100% without touching per-wave
// code: 512-thread blocks, TWO n-sites per block (waves 0-3 -> n=2np,
// waves 4-7 -> n=2np+1). Sites live in different waves, so there is no
// cross-main-loop register residency (the R15/R16 spill mode). LDS = 2 tiles
// = 27.8 KB -> 4 blocks/CU x 8 waves = 32 waves/CU cap (was 20).
// Per-wave structure identical to R18: K=16 MFMA, 2 shift-copies, 1
// ds_read2_b32 gather per MFMA, fence-pinned double buffer, batched epilogue
// reduction, log2e-folded weights (raw exp2), DPP quad-max pool.
// Spill control: WRITE_SIZE must stay ~16.6 MB.

typedef _Float16 half4 __attribute__((ext_vector_type(4)));
typedef float f32x4 __attribute__((ext_vector_type(4)));
union H4 { int2 i; half4 h; };

template <int CTRL>
__device__ __forceinline__ float dpp_max(float x) {
  int xi = __builtin_bit_cast(int, x);
  int yi = __builtin_amdgcn_update_dpp(xi, xi, CTRL, 0xf, 0xf, false);
  return fmaxf(x, __builtin_bit_cast(float, yi));
}
// quad_perm ctrls: xor1 = [1,0,3,2] = 0xB1, xor2 = [2,3,0,1] = 0x4E

// Frag-ready weights for K=16, pre-scaled by log2(e): wsA[v][lane] = 4 halves
// A[c=lane&15][k=16v+4g+j], tap G = 4v+g, kw = j; zero for G>=27 or kw==3.
__global__ void wtrans(const float* __restrict__ w, int2* __restrict__ wsA) {
  int t = threadIdx.x;            // 448 threads: v = t>>6, lane = t&63
  if (t >= 448) return;
  int v = t >> 6, l = t & 63;
  int c = l & 15, g = l >> 4;
  int G = 4 * v + g;
  unsigned hh[4];
  for (int j = 0; j < 4; ++j) {
    float val = (G < 27 && j < 3) ? w[c * 81 + G * 3 + j] * 1.44269504088896f
                                  : 0.0f;
    __half h = __float2half(val);
    hh[j] = (unsigned)__half_as_ushort(h);
  }
  int2 o;
  o.x = (int)(hh[0] | (hh[1] << 16));
  o.y = (int)(hh[2] | (hh[3] << 16));
  wsA[v * 64 + l] = o;
}

__global__ __launch_bounds__(512, 5) void conv_sm_pool(
    const float* __restrict__ x, const int2* __restrict__ wsA,
    const float* __restrict__ b, float* __restrict__ out) {
  // Per site: 2 shifted copies of the 3456-half tile stream (copy1 =
  // shift-1-half), copy stride 1736 ints, rows unpadded (16 ints).
  // Gather: half-window Q..Q+3 -> copy Q&1, int index Q>>1 via ds_read2_b32.
  // After the main loop each site's tile is reused as its pool buffer.
  __shared__ int lds[2][3472];

  const int tid = threadIdx.x;
  const int blk = blockIdx.x;                  // 5376 blocks
  const int np = blk / 21, rr = blk % 21, pd = rr / 7, ph = rr % 7;

  const int site = tid >> 8;                   // waves 0-3: site 0, 4-7: site 1
  const int lane = tid & 63;
  const int dd = (tid >> 6) & 3;               // wave-within-site = dd slice
  const int l15 = lane & 15, g = lane >> 4;

  // ---- setup (identical per wave; hoisted above staging) ----
  H4 wa[7];
#pragma unroll
  for (int v = 0; v < 7; ++v) wa[v].i = wsA[v * 64 + lane];

  float4 b4 = *reinterpret_cast<const float4*>(b + 4 * g);

  // tap-group int offsets: T = cin*576 + kd*96 + kh*16 for G = 4v+g (clamped)
  int tvi[7];
#pragma unroll
  for (int v = 0; v < 7; ++v) {
    int G = 4 * v + g;
    if (G > 26) G = 26;
    int cin = G / 9, r = G % 9;
    tvi[v] = cin * 576 + (r / 3) * 96 + (r % 3) * 16;
  }

  // position bases: P = dd*192 + dh*32 + wp (halves); pbi = (P>>1)+(P&1)*1736
  int pbi[7];
#pragma unroll
  for (int tl = 0; tl < 7; ++tl) {
    int rem = tl * 16;
    int dh0 = rem / 28, rem28 = rem % 28;
    int bump = (rem28 + l15) >= 28 ? 1 : 0;
    int P = dd * 192 + (dh0 + bump) * 32 + (rem28 + l15 - 28 * bump);
    pbi[tl] = (P >> 1) + (P & 1) * 1736;
  }

  // ---- stage both sites' tiles: 432 units (site, row, seg), one/thread ----
  const float* xb0 = x + (size_t)(np * 2) * 49152
                   + (size_t)(4 * pd) * 1024 + (size_t)(4 * ph) * 32;
  if (tid < 432) {
    int su = (tid >= 216) ? 1 : 0;
    int r = tid - su * 216;
    int row = r >> 1, seg = r & 1;            // row = cin*36 + ld*6 + lh
    int lh = row % 6, t2 = row / 6, ld = t2 % 6, cin = t2 / 6;
    const float* src = xb0 + (size_t)su * 49152
                     + ((cin * 16 + ld) * 32 + lh) * 32 + seg * 16;
    float4 f0 = *reinterpret_cast<const float4*>(src);
    float4 f1 = *reinterpret_cast<const float4*>(src + 4);
    float4 f2 = *reinterpret_cast<const float4*>(src + 8);
    float4 f3 = *reinterpret_cast<const float4*>(src + 12);
    float ex = src[16];
    int c[8];
    __half2 h;
    h = __float22half2_rn(make_float2(f0.x, f0.y)); c[0] = *reinterpret_cast<int*>(&h);
    h = __float22half2_rn(make_float2(f0.z, f0.w)); c[1] = *reinterpret_cast<int*>(&h);
    h = __float22half2_rn(make_float2(f1.x, f1.y)); c[2] = *reinterpret_cast<int*>(&h);
    h = __float22half2_rn(make_float2(f1.z, f1.w)); c[3] = *reinterpret_cast<int*>(&h);
    h = __float22half2_rn(make_float2(f2.x, f2.y)); c[4] = *reinterpret_cast<int*>(&h);
    h = __float22half2_rn(make_float2(f2.z, f2.w)); c[5] = *reinterpret_cast<int*>(&h);
    h = __float22half2_rn(make_float2(f3.x, f3.y)); c[6] = *reinterpret_cast<int*>(&h);
    h = __float22half2_rn(make_float2(f3.z, f3.w)); c[7] = *reinterpret_cast<int*>(&h);
    int eh = (int)__half_as_ushort(__float2half(ex));
    int s[8];
#pragma unroll
    for (int k = 0; k < 7; ++k) s[k] = __builtin_amdgcn_alignbit(c[k + 1], c[k], 16);
    s[7] = __builtin_amdgcn_alignbit(eh, c[7], 16);
    int li = row * 16 + seg * 8;
    int* buf = &lds[su][0];
    int4 w0; w0.x = c[0]; w0.y = c[1]; w0.z = c[2]; w0.w = c[3];
    int4 w1; w1.x = c[4]; w1.y = c[5]; w1.z = c[6]; w1.w = c[7];
    *reinterpret_cast<int4*>(&buf[li])     = w0;
    *reinterpret_cast<int4*>(&buf[li + 4]) = w1;
    int4 w2; w2.x = s[0]; w2.y = s[1]; w2.z = s[2]; w2.w = s[3];
    int4 w3; w3.x = s[4]; w3.y = s[5]; w3.z = s[6]; w3.w = s[7];
    *reinterpret_cast<int4*>(&buf[1736 + li])     = w2;
    *reinterpret_cast<int4*>(&buf[1736 + li + 4]) = w3;
  }
  __syncthreads();

  // acc init with bias (row = channel = 4g+q), log2e pre-scaled
  f32x4 acc[7];
  f32x4 binit;
  binit[0] = b4.x * 1.44269504088896f;
  binit[1] = b4.y * 1.44269504088896f;
  binit[2] = b4.z * 1.44269504088896f;
  binit[3] = b4.w * 1.44269504088896f;
#pragma unroll
  for (int tl = 0; tl < 7; ++tl) acc[tl] = binit;

  // ---- main: 7 K-windows x 7 N-tiles, double-buffered, fence-pinned ----
  const int* Bp = &lds[site][0];
  H4 bfA[7], bfB[7];
#pragma unroll
  for (int tl = 0; tl < 7; ++tl) {
    const int* p = &Bp[pbi[tl] + tvi[0]];
    bfA[tl].i.x = p[0]; bfA[tl].i.y = p[1];
  }
  __builtin_amdgcn_sched_barrier(0);
#pragma unroll
  for (int vv = 0; vv < 3; ++vv) {
    const int v0 = 2 * vv, v1 = 2 * vv + 1, v2 = 2 * vv + 2;
#pragma unroll
    for (int tl = 0; tl < 7; ++tl) {
      const int* p = &Bp[pbi[tl] + tvi[v1]];
      bfB[tl].i.x = p[0]; bfB[tl].i.y = p[1];
    }
    __builtin_amdgcn_sched_barrier(0);
#pragma unroll
    for (int tl = 0; tl < 7; ++tl)
      acc[tl] = __builtin_amdgcn_mfma_f32_16x16x16f16(wa[v0].h, bfA[tl].h, acc[tl], 0, 0, 0);
    __builtin_amdgcn_sched_barrier(0);
#pragma unroll
    for (int tl = 0; tl < 7; ++tl) {
      const int* p = &Bp[pbi[tl] + tvi[v2]];
      bfA[tl].i.x = p[0]; bfA[tl].i.y = p[1];
    }
    __builtin_amdgcn_sched_barrier(0);
#pragma unroll
    for (int tl = 0; tl < 7; ++tl)
      acc[tl] = __builtin_amdgcn_mfma_f32_16x16x16f16(wa[v1].h, bfB[tl].h, acc[tl], 0, 0, 0);
    __builtin_amdgcn_sched_barrier(0);
  }
#pragma unroll
  for (int tl = 0; tl < 7; ++tl)
    acc[tl] = __builtin_amdgcn_mfma_f32_16x16x16f16(wa[6].h, bfA[tl].h, acc[tl], 0, 0, 0);

  // ---- epilogue: softmax over channels (batched reductions), pool ----
  __syncthreads();      // all mains done -> each site's tile reusable as pool
  float* pool2 = reinterpret_cast<float*>(&lds[site][0]);  // [dd*4+dh][pw][c]

  // phase 1: exp2 in place (acc regs reused), per-tile channel-group sums
  float s4[7];
#pragma unroll
  for (int tl = 0; tl < 7; ++tl) {
#pragma unroll
    for (int q = 0; q < 4; ++q) acc[tl][q] = __builtin_amdgcn_exp2f(acc[tl][q]);
    s4[tl] = (acc[tl][0] + acc[tl][1]) + (acc[tl][2] + acc[tl][3]);
  }
  // phase 2: batched cross-group butterflies (7 independent chains pipeline)
  float t7[7];
#pragma unroll
  for (int tl = 0; tl < 7; ++tl) t7[tl] = __shfl_xor(s4[tl], 16, 64);
#pragma unroll
  for (int tl = 0; tl < 7; ++tl) s4[tl] += t7[tl];
#pragma unroll
  for (int tl = 0; tl < 7; ++tl) t7[tl] = __shfl_xor(s4[tl], 32, 64);
#pragma unroll
  for (int tl = 0; tl < 7; ++tl) s4[tl] += t7[tl];
#pragma unroll
  for (int tl = 0; tl < 7; ++tl) s4[tl] = __builtin_amdgcn_rcpf(s4[tl]);

  // phase 3: normalize, DPP quad-max, pool write
#pragma unroll
  for (int tl = 0; tl < 7; ++tl) {
    float pm[4];
#pragma unroll
    for (int q = 0; q < 4; ++q) pm[q] = acc[tl][q] * s4[tl];
#pragma unroll
    for (int q = 0; q < 4; ++q) {
      pm[q] = dpp_max<0xB1>(pm[q]);   // wp xor1
      pm[q] = dpp_max<0x4E>(pm[q]);   // wp xor2
    }
    if ((l15 & 3) == 0) {
      int rem = tl * 16;
      int dh0 = rem / 28, rem28 = rem % 28;
      int bump = (rem28 + l15) >= 28 ? 1 : 0;
      int dh = dh0 + bump;
      int pw = (rem28 + l15 - 28 * bump) >> 2;
      float4 val = {pm[0], pm[1], pm[2], pm[3]};
      *reinterpret_cast<float4*>(&pool2[(((dd * 4 + dh) * 7 + pw) << 4) + 4 * g]) = val;
    }
  }
  __syncthreads();

  // tail: 448 threads cover both sites; pair (2k,2k+1) splits 16 slots 8/8
  if (tid < 448) {
    int ts = (tid >= 224) ? 1 : 0;
    int t = tid - ts * 224;
    int idx = t >> 1, h = t & 1;
    int c = idx / 7, pw = idx % 7;
    const float* pp = reinterpret_cast<const float*>(&lds[ts][0]);
    float m = pp[(((h * 8) * 7 + pw) << 4) + c];
#pragma unroll
    for (int s2 = 1; s2 < 8; ++s2)
      m = fmaxf(m, pp[(((h * 8 + s2) * 7 + pw) << 4) + c]);
    m = dpp_max<0xB1>(m);   // combine with partner (lanes 2k,2k+1)
    if (h == 0)
      out[(((size_t)(np * 2 + ts) * 16 + c) * 3 + pd) * 49 + (size_t)ph * 7 + pw] = m;
  }
}

extern "C" void kernel_launch(void* const* d_in, const int* in_sizes, int n_in,
                              void* d_out, int out_size, void* d_ws, size_t ws_size,
                              hipStream_t stream) {
  const float* x = (const float*)d_in[0];
  const float* w = (const float*)d_in[1];
  const float* b = (const float*)d_in[2];
  float* out = (float*)d_out;
  int2* wsA = (int2*)d_ws;   // 7 windows * 64 lanes * 8 B = 3584 B
  (void)in_sizes; (void)n_in; (void)out_size; (void)ws_size;
  hipLaunchKernelGGL(wtrans, dim3(1), dim3(448), 0, stream, w, wsA);
  hipLaunchKernelGGL(conv_sm_pool, dim3(256 * 21), dim3(512), 0, stream,
                     x, wsA, b, out);
}

// Round 10
// 188.278 us; speedup vs baseline: 1.0876x; 1.0876x over previous
//
#include <hip/hip_runtime.h>
#include <hip/hip_fp16.h>

// Fused Conv3d(3->16, 3x3x3, VALID) + bias + channel softmax + maxpool(4,4,4)/4.
// x: [512,3,16,32,32] f32, w: [16,3,3,3,3] f32, b: [16] f32 -> out [512,16,3,7,7] f32
//
// R20: R19's 512-thread/2-site blocks regressed (occupancy 49->40, coarser
// scheduling quantum) -- reverted to the R18 structure (74.0 us best).
// R18's top pipe is VALU (73%); a large share is index math identical for all
// 10752 blocks (tvi magic-divisions, pbi/poolIdx, staging row/seg, tail /7%7).
// R20 precomputes ALL of it in wtrans into d_ws tables (~26 KB, L2-hot):
//   - wa frags (as before)            ints [0,896)
//   - tvi per lane (8-int stride)     ints [896,1408)
//   - pbi[7]+poolIdx[7] per (dd,lane) ints [1408,5504), 16-int stride
//   - staging {goff,li} per tid       ints [5504,6016)
//   - tail {tailBase,tOff} per tid    ints [6016,6528)
// Conv setup: ~15 coalesced vector loads instead of ~200 VALU.
// Liveness discipline (R15-R17 lesson): poolIdx/tail tables are loaded AFTER
// the main loop so registers live across the fence-pinned MFMA region are
// identical to R18. Spill control: WRITE_SIZE must stay ~16.6 MB, VGPR ~48.
// Main loop/epilogue otherwise identical to R18: K=16 MFMA, 2 shift-copies,
// ds_read2_b32 gather, fence-pinned double buffer, batched softmax reduction,
// log2e-folded weights (raw exp2), DPP quad-max pool.

typedef _Float16 half4 __attribute__((ext_vector_type(4)));
typedef float f32x4 __attribute__((ext_vector_type(4)));
union H4 { int2 i; half4 h; };

template <int CTRL>
__device__ __forceinline__ float dpp_max(float x) {
  int xi = __builtin_bit_cast(int, x);
  int yi = __builtin_amdgcn_update_dpp(xi, xi, CTRL, 0xf, 0xf, false);
  return fmaxf(x, __builtin_bit_cast(float, yi));
}
// quad_perm ctrls: xor1 = [1,0,3,2] = 0xB1, xor2 = [2,3,0,1] = 0x4E

// Precompute weight frags (log2e-scaled) + every per-lane index table.
__global__ void wtrans(const float* __restrict__ w, int* __restrict__ ws) {
  int t = threadIdx.x;            // 512 threads, 1 block
  // ---- wa frags: t in [0,448): v = t>>6, lane = t&63 ----
  if (t < 448) {
    int v = t >> 6, l = t & 63;
    int c = l & 15, g = l >> 4;
    int G = 4 * v + g;
    unsigned hh[4];
    for (int j = 0; j < 4; ++j) {
      float val = (G < 27 && j < 3) ? w[c * 81 + G * 3 + j] * 1.44269504088896f
                                    : 0.0f;
      hh[j] = (unsigned)__half_as_ushort(__float2half(val));
    }
    ws[2 * t]     = (int)(hh[0] | (hh[1] << 16));
    ws[2 * t + 1] = (int)(hh[2] | (hh[3] << 16));
  }
  // ---- tvi per lane: T = cin*576 + kd*96 + kh*16 ints for G = 4v+g ----
  if (t < 64) {
    int g = t >> 4;
    for (int v = 0; v < 7; ++v) {
      int G = 4 * v + g;
      if (G > 26) G = 26;
      int cin = G / 9, r = G % 9;
      ws[896 + t * 8 + v] = cin * 576 + (r / 3) * 96 + (r % 3) * 16;
    }
    ws[896 + t * 8 + 7] = 0;
  }
  if (t < 256) {
    // ---- pbi + poolIdx per (dd = t>>6, lane = t&63) ----
    int lane = t & 63, dd = t >> 6;
    int l15 = lane & 15, g = lane >> 4;
    int base = 1408 + t * 16;
    for (int tl = 0; tl < 7; ++tl) {
      int rem = tl * 16;
      int dh0 = rem / 28, rem28 = rem % 28;
      int bump = (rem28 + l15) >= 28 ? 1 : 0;
      int wp = rem28 + l15 - 28 * bump;
      int dh = dh0 + bump;
      int P = dd * 192 + dh * 32 + wp;
      ws[base + tl]     = (P >> 1) + (P & 1) * 1736;
      ws[base + 8 + tl] = (((dd * 4 + dh) * 7 + (wp >> 2)) << 4) + 4 * g;
    }
    ws[base + 7] = 0; ws[base + 15] = 0;
    // ---- staging {goff, li} per tid (only tid<216 used by conv) ----
    int row = t >> 1, seg = t & 1;            // row = cin*36 + ld*6 + lh
    int lh = row % 6, t2 = row / 6, ld = t2 % 6, cin2 = t2 / 6;
    ws[5504 + t * 2]     = ((cin2 * 16 + ld) * 32 + lh) * 32 + seg * 16;
    ws[5504 + t * 2 + 1] = row * 16 + seg * 8;
    // ---- tail {tailBase, tOff} per tid (only tid<224 used) ----
    int idx = t >> 1, h = t & 1;
    int c = idx / 7, pw = idx % 7;
    ws[6016 + t * 2]     = ((h * 8) * 7 + pw) * 16 + c;
    ws[6016 + t * 2 + 1] = c * 147 + pw;      // (c*3)*49 + pw
  }
}

__global__ __launch_bounds__(256, 5) void conv_sm_pool(
    const float* __restrict__ x, const int* __restrict__ ws,
    const float* __restrict__ b, float* __restrict__ out) {
  // 2 shifted copies of the 3456-half tile stream (copy1 = shift-1-half),
  // copy stride 1736 ints. Rows unpadded: row (cin,ld,lh) = 32 halves = 16 ints.
  // Gather: half-window Q..Q+3 -> copy Q&1, int index Q>>1 via ds_read2_b32.
  // After the main loop, reused as pool buffer [dd*4+dh][pw][c].
  __shared__ int lds[3472];

  const int tid = threadIdx.x;
  const int blk = blockIdx.x;
  const int n = blk / 21, rr = blk % 21, pd = rr / 7, ph = rr % 7;

  const int lane = tid & 63;
  const int l15 = lane & 15, g = lane >> 4;

  // ---- setup: pure table loads (coalesced, L2-hot) ----
  H4 wa[7];
#pragma unroll
  for (int v = 0; v < 7; ++v)
    wa[v].i = reinterpret_cast<const int2*>(ws)[v * 64 + lane];

  int4 tv0 = *reinterpret_cast<const int4*>(&ws[896 + lane * 8]);
  int4 tv1 = *reinterpret_cast<const int4*>(&ws[896 + lane * 8 + 4]);
  int tvi[7] = {tv0.x, tv0.y, tv0.z, tv0.w, tv1.x, tv1.y, tv1.z};

  int4 pq0 = *reinterpret_cast<const int4*>(&ws[1408 + tid * 16]);
  int4 pq1 = *reinterpret_cast<const int4*>(&ws[1408 + tid * 16 + 4]);
  int pbi[7] = {pq0.x, pq0.y, pq0.z, pq0.w, pq1.x, pq1.y, pq1.z};

  int2 stg = *reinterpret_cast<const int2*>(&ws[5504 + tid * 2]);  // goff, li

  float4 b4 = *reinterpret_cast<const float4*>(b + 4 * g);

  // ---- stage both copies, loop-free: 216 threads, one (row,seg) each ----
  const float* xb = x + ((size_t)n * 3 * 16 * 32 * 32)
                  + (size_t)(4 * pd) * 1024 + (size_t)(4 * ph) * 32;
  if (tid < 216) {
    const float* src = &xb[stg.x];
    float4 f0 = *reinterpret_cast<const float4*>(src);
    float4 f1 = *reinterpret_cast<const float4*>(src + 4);
    float4 f2 = *reinterpret_cast<const float4*>(src + 8);
    float4 f3 = *reinterpret_cast<const float4*>(src + 12);
    float ex = src[16];
    int c[8];
    __half2 h;
    h = __float22half2_rn(make_float2(f0.x, f0.y)); c[0] = *reinterpret_cast<int*>(&h);
    h = __float22half2_rn(make_float2(f0.z, f0.w)); c[1] = *reinterpret_cast<int*>(&h);
    h = __float22half2_rn(make_float2(f1.x, f1.y)); c[2] = *reinterpret_cast<int*>(&h);
    h = __float22half2_rn(make_float2(f1.z, f1.w)); c[3] = *reinterpret_cast<int*>(&h);
    h = __float22half2_rn(make_float2(f2.x, f2.y)); c[4] = *reinterpret_cast<int*>(&h);
    h = __float22half2_rn(make_float2(f2.z, f2.w)); c[5] = *reinterpret_cast<int*>(&h);
    h = __float22half2_rn(make_float2(f3.x, f3.y)); c[6] = *reinterpret_cast<int*>(&h);
    h = __float22half2_rn(make_float2(f3.z, f3.w)); c[7] = *reinterpret_cast<int*>(&h);
    int eh = (int)__half_as_ushort(__float2half(ex));
    int s[8];
#pragma unroll
    for (int k = 0; k < 7; ++k) s[k] = __builtin_amdgcn_alignbit(c[k + 1], c[k], 16);
    s[7] = __builtin_amdgcn_alignbit(eh, c[7], 16);
    int li = stg.y;
    int4 w0; w0.x = c[0]; w0.y = c[1]; w0.z = c[2]; w0.w = c[3];
    int4 w1; w1.x = c[4]; w1.y = c[5]; w1.z = c[6]; w1.w = c[7];
    *reinterpret_cast<int4*>(&lds[li])     = w0;
    *reinterpret_cast<int4*>(&lds[li + 4]) = w1;
    int4 w2; w2.x = s[0]; w2.y = s[1]; w2.z = s[2]; w2.w = s[3];
    int4 w3; w3.x = s[4]; w3.y = s[5]; w3.z = s[6]; w3.w = s[7];
    *reinterpret_cast<int4*>(&lds[1736 + li])     = w2;
    *reinterpret_cast<int4*>(&lds[1736 + li + 4]) = w3;
  }
  __syncthreads();

  // acc init with bias (row = channel = 4g+q), log2e pre-scaled
  f32x4 acc[7];
  f32x4 binit;
  binit[0] = b4.x * 1.44269504088896f;
  binit[1] = b4.y * 1.44269504088896f;
  binit[2] = b4.z * 1.44269504088896f;
  binit[3] = b4.w * 1.44269504088896f;
#pragma unroll
  for (int tl = 0; tl < 7; ++tl) acc[tl] = binit;

  // ---- main: 7 K-windows x 7 N-tiles, double-buffered, fence-pinned ----
  H4 bfA[7], bfB[7];
#pragma unroll
  for (int tl = 0; tl < 7; ++tl) {
    const int* p = &lds[pbi[tl] + tvi[0]];
    bfA[tl].i.x = p[0]; bfA[tl].i.y = p[1];
  }
  __builtin_amdgcn_sched_barrier(0);
#pragma unroll
  for (int vv = 0; vv < 3; ++vv) {
    const int v0 = 2 * vv, v1 = 2 * vv + 1, v2 = 2 * vv + 2;
#pragma unroll
    for (int tl = 0; tl < 7; ++tl) {
      const int* p = &lds[pbi[tl] + tvi[v1]];
      bfB[tl].i.x = p[0]; bfB[tl].i.y = p[1];
    }
    __builtin_amdgcn_sched_barrier(0);
#pragma unroll
    for (int tl = 0; tl < 7; ++tl)
      acc[tl] = __builtin_amdgcn_mfma_f32_16x16x16f16(wa[v0].h, bfA[tl].h, acc[tl], 0, 0, 0);
    __builtin_amdgcn_sched_barrier(0);
#pragma unroll
    for (int tl = 0; tl < 7; ++tl) {
      const int* p = &lds[pbi[tl] + tvi[v2]];
      bfA[tl].i.x = p[0]; bfA[tl].i.y = p[1];
    }
    __builtin_amdgcn_sched_barrier(0);
#pragma unroll
    for (int tl = 0; tl < 7; ++tl)
      acc[tl] = __builtin_amdgcn_mfma_f32_16x16x16f16(wa[v1].h, bfB[tl].h, acc[tl], 0, 0, 0);
    __builtin_amdgcn_sched_barrier(0);
  }
#pragma unroll
  for (int tl = 0; tl < 7; ++tl)
    acc[tl] = __builtin_amdgcn_mfma_f32_16x16x16f16(wa[6].h, bfA[tl].h, acc[tl], 0, 0, 0);

  // ---- epilogue: softmax over channels (batched reductions), pool ----
  __syncthreads();      // all LDS tile reads done; reuse lds as pool buffer
  float* pool2 = reinterpret_cast<float*>(lds);   // [dd*4+dh][pw][c]

  // poolIdx table loaded only now (keeps main-loop register set == R18)
  int4 pq2 = *reinterpret_cast<const int4*>(&ws[1408 + tid * 16 + 8]);
  int4 pq3 = *reinterpret_cast<const int4*>(&ws[1408 + tid * 16 + 12]);
  int poolIdx[7] = {pq2.x, pq2.y, pq2.z, pq2.w, pq3.x, pq3.y, pq3.z};

  // phase 1: exp2 in place (acc regs reused), per-tile channel-group sums
  float s4[7];
#pragma unroll
  for (int tl = 0; tl < 7; ++tl) {
#pragma unroll
    for (int q = 0; q < 4; ++q) acc[tl][q] = __builtin_amdgcn_exp2f(acc[tl][q]);
    s4[tl] = (acc[tl][0] + acc[tl][1]) + (acc[tl][2] + acc[tl][3]);
  }
  // phase 2: batched cross-group butterflies (7 independent chains pipeline)
  float t7[7];
#pragma unroll
  for (int tl = 0; tl < 7; ++tl) t7[tl] = __shfl_xor(s4[tl], 16, 64);
#pragma unroll
  for (int tl = 0; tl < 7; ++tl) s4[tl] += t7[tl];
#pragma unroll
  for (int tl = 0; tl < 7; ++tl) t7[tl] = __shfl_xor(s4[tl], 32, 64);
#pragma unroll
  for (int tl = 0; tl < 7; ++tl) s4[tl] += t7[tl];
#pragma unroll
  for (int tl = 0; tl < 7; ++tl) s4[tl] = __builtin_amdgcn_rcpf(s4[tl]);

  // phase 3: normalize, DPP quad-max, pool write (indices from table)
#pragma unroll
  for (int tl = 0; tl < 7; ++tl) {
    float pm[4];
#pragma unroll
    for (int q = 0; q < 4; ++q) pm[q] = acc[tl][q] * s4[tl];
#pragma unroll
    for (int q = 0; q < 4; ++q) {
      pm[q] = dpp_max<0xB1>(pm[q]);   // wp xor1
      pm[q] = dpp_max<0x4E>(pm[q]);   // wp xor2
    }
    if ((l15 & 3) == 0) {
      float4 val = {pm[0], pm[1], pm[2], pm[3]};
      *reinterpret_cast<float4*>(&pool2[poolIdx[tl]]) = val;
    }
  }
  __syncthreads();

  // tail: pair (tid, tid^1) split the 16 slots 8/8, DPP pair-max
  if (tid < 224) {
    int2 tlt = *reinterpret_cast<const int2*>(&ws[6016 + tid * 2]);
    int h = tid & 1;
    float m = pool2[tlt.x];
#pragma unroll
    for (int s2 = 1; s2 < 8; ++s2)
      m = fmaxf(m, pool2[tlt.x + s2 * 112]);
    m = dpp_max<0xB1>(m);   // combine with partner (lanes 2k,2k+1)
    if (h == 0)
      out[(size_t)n * 2352 + tlt.y + pd * 49 + ph * 7] = m;
  }
}

extern "C" void kernel_launch(void* const* d_in, const int* in_sizes, int n_in,
                              void* d_out, int out_size, void* d_ws, size_t ws_size,
                              hipStream_t stream) {
  const float* x = (const float*)d_in[0];
  const float* w = (const float*)d_in[1];
  const float* b = (const float*)d_in[2];
  float* out = (float*)d_out;
  int* ws = (int*)d_ws;    // 6528 ints = 26.1 KB of precomputed tables
  (void)in_sizes; (void)n_in; (void)out_size; (void)ws_size;
  hipLaunchKernelGGL(wtrans, dim3(1), dim3(512), 0, stream, w, ws);
  hipLaunchKernelGGL(conv_sm_pool, dim3(512 * 3 * 7), dim3(256), 0, stream,
                     x, ws, b, out);
}